// Round 4
// 2041.167 us; speedup vs baseline: 1.2929x; 1.2929x over previous
//
#include <hip/hip_runtime.h>
#include <stdint.h>

#define BATCH 256
#define SEQT  512
#define INSZ  256
#define HID   512

typedef __attribute__((ext_vector_type(8))) short short8;
typedef __attribute__((ext_vector_type(4))) float floatx4;
typedef __attribute__((ext_vector_type(2))) float floatx2;
typedef __attribute__((ext_vector_type(4))) float float4v;
typedef unsigned long long u64;

// Sentinel: bf16 0x7F7F ~= 3.4e38. h = o*tanh(c) has |h| < 1 (bf16 mag
// <= 0x3F80), so 0x7F7F can NEVER be a valid h value. Byte pattern 0x7F
// is memset-able.
#define SENT32 0x7F7F7F7Fu

__device__ __forceinline__ ushort f2b(float f) {
    union { float f; uint i; } v; v.f = f;
    uint r = (v.i + 0x7FFFu + ((v.i >> 16) & 1u)) >> 16;
    return (ushort)r;
}
__device__ __forceinline__ float fsigmoid(float x) {
    float e = __builtin_amdgcn_exp2f(-1.44269504f * x);
    return __builtin_amdgcn_rcpf(1.0f + e);
}
__device__ __forceinline__ float ftanh(float x) {
    float e = __builtin_amdgcn_exp2f(-2.88539008f * x);
    return 2.0f * __builtin_amdgcn_rcpf(1.0f + e) - 1.0f;
}

// Convert x fp32 -> bf16, same [B][T][I] layout. 4 elements/thread.
__global__ __launch_bounds__(256) void pack_x(
    const float4v* __restrict__ x, ushort* __restrict__ xp)
{
    uint idx = blockIdx.x * 256u + threadIdx.x;
    float4v v = x[idx];
    ushort4 o;
    o.x = f2b(v[0]); o.y = f2b(v[1]); o.z = f2b(v[2]); o.w = f2b(v[3]);
    *(ushort4*)&xp[idx * 4u] = o;
}

// Pack the 8 fp32 weight matrices into bf16 MFMA B-fragment layout.
__global__ __launch_bounds__(256) void pack_weights(
    const float* __restrict__ whi, const float* __restrict__ whf,
    const float* __restrict__ whg, const float* __restrict__ who,
    const float* __restrict__ wui, const float* __restrict__ wuf,
    const float* __restrict__ wug, const float* __restrict__ wuo,
    ushort* __restrict__ whp, ushort* __restrict__ wup)
{
    uint idx = blockIdx.x * 256u + threadIdx.x;
    if (idx < (1u << 20)) {
        uint n = idx & 15u, j = (idx >> 4) & 7u;
        uint k8 = (idx >> 7) & 63u, c16 = (idx >> 13) & 31u, q = idx >> 18;
        const float* w = (q == 0) ? whi : (q == 1) ? whf : (q == 2) ? whg : who;
        float v = w[(k8 * 8u + j) * HID + c16 * 16u + n];
        whp[(((q * 32u + c16) * 64u + k8) * 16u + n) * 8u + j] = f2b(v);
    } else {
        uint idx2 = idx - (1u << 20);
        if (idx2 < (1u << 19)) {
            uint n = idx2 & 15u, j = (idx2 >> 4) & 7u;
            uint k8 = (idx2 >> 7) & 31u, c16 = (idx2 >> 12) & 31u, q = idx2 >> 17;
            const float* w = (q == 0) ? wui : (q == 1) ? wuf : (q == 2) ? wug : wuo;
            float v = w[(k8 * 8u + j) * HID + c16 * 16u + n];
            wup[(((q * 32u + c16) * 32u + k8) * 16u + n) * 8u + j] = f2b(v);
        }
    }
}

// Persistent LSTM, flag-free sentinel exchange (all system-scope ops).
//
// 4 rotating h buffers, buf[s%4] holds h_s. Readiness is in-band: a
// consumer polls its 64B h lines until no dword == SENT32 (each dword is
// written by exactly one thread's single store -> no sub-dword tearing).
// Producers at step t additionally store SENT32 into buf[(t+2)%4] (the
// h_{t-2} slot). Safety/liveness proof sketch:
//  - skew <= 1 step: reaching t+1 requires having staged EVERYONE's h_t.
//  - reset target legality: anyone at step t has staged all h_{t-1}, so
//    everyone finished staging h_{t-2} -> buf[(t+2)%4] has no readers.
//  - reset visibility: step-t's end vmcnt(0) commits resets before any
//    step-t+1 h store issues; a consumer only polls buf[(t+2)%4] (at step
//    t+3) after accepting h lines whose commit postdates those resets.
//  - concurrent polls target buf[(t-1)%4] / buf[t%4] only; the reset
//    targets buf[(t+2)%4]; h writes target buf[t%4] (the polled data).
// Launch-idempotent: bufs 0,1 memset to 0x7F host-side each launch; bufs
// 2,3 reset in-kernel at steps 0,1 before they are ever polled (steps 3,4).
__global__ __launch_bounds__(256, 1) void lstm_persist(
    const short8* __restrict__ xp,   // [B][T][I] bf16 as short8
    const short8* __restrict__ whp,  // packed, q-stride 32768 (short8)
    const short8* __restrict__ wup,  // packed, q-stride 16384 (short8)
    const float* __restrict__ bi, const float* __restrict__ bfr,
    const float* __restrict__ bg, const float* __restrict__ bo,
    ushort* __restrict__ hb,         // 4 x 256KB h buffers, [k8(64)][b(256)][j(8)]
    float* __restrict__ out)
{
    __shared__ short8 hstage[1088];       // [k8(64)] stride 17 [b(16)]
    __shared__ float  gtile[4 * 16 * 34]; // [gate][b_local(16)][u_local pad 34]

    const uint blk = blockIdx.x;
    const uint rg = blk >> 4, ug = blk & 15u;
    const uint bbase = rg * 16u;
    const uint tid = threadIdx.x;
    const uint lane = tid & 63u;
    const uint q = tid >> 6;              // gate index = wave
    const uint m = lane & 15u, quad = lane >> 4;
    const uint b_row = bbase + m;

    // ---- weights -> registers (once) ----
    short8 wH[16][2];
    short8 wX[8][2];
    {
        const uint qh = q * 32768u, qx = q * 16384u;
        #pragma unroll
        for (int it = 0; it < 16; ++it) {
            uint k8 = (uint)it * 4u + quad;
            #pragma unroll
            for (int s = 0; s < 2; ++s) {
                uint c16 = ug * 2u + (uint)s;
                wH[it][s] = whp[qh + (c16 * 64u + k8) * 16u + m];
            }
        }
        #pragma unroll
        for (int kx = 0; kx < 8; ++kx) {
            #pragma unroll
            for (int s = 0; s < 2; ++s) {
                uint c16 = ug * 2u + (uint)s;
                wX[kx][s] = wup[qx + (c16 * 32u + (uint)kx * 4u + quad) * 16u + m];
            }
        }
    }

    // ---- epilogue ownership: 2 adjacent units x 1 row per thread ----
    const uint eb = tid & 15u;
    const uint eu = (tid >> 4) * 2u;
    const uint gb = bbase + eb;
    const uint gu = ug * 32u + eu;
    float c0 = 0.f, c1 = 0.f;
    const float vbi0 = bi[gu],  vbi1 = bi[gu + 1];
    const float vbf0 = bfr[gu], vbf1 = bfr[gu + 1];
    const float vbg0 = bg[gu],  vbg1 = bg[gu + 1];
    const float vbo0 = bo[gu],  vbo1 = bo[gu + 1];
    const uint hidx = (((gu >> 3) * 256u + gb) * 8u + (gu & 7u)) >> 1; // dword idx

    // ---- staging ownership: 64 contiguous bytes per thread ----
    const uint sk8 = tid >> 2;            // k8 row 0..63
    const uint sqt = tid & 3u;            // quarter of the 16-row slice
    const uint soff = (sk8 * 256u + bbase) * 16u + sqt * 64u;   // byte offset

    // ---- x prefetch for t=0 ----
    short8 xa[8];
    #pragma unroll
    for (int kx = 0; kx < 8; ++kx)
        xa[kx] = xp[(b_row * SEQT + 0u) * 32u + (uint)kx * 4u + quad];

    for (int t = 0; t < SEQT; ++t) {
        // prefetch x for t+1
        short8 xn[8];
        {
            uint tn = (t + 1 < SEQT) ? (uint)(t + 1) : (uint)t;
            #pragma unroll
            for (int kx = 0; kx < 8; ++kx)
                xn[kx] = xp[(b_row * SEQT + tn) * 32u + (uint)kx * 4u + quad];
        }
        // x-path MFMAs (independent of h)
        floatx4 acc0 = {}, acc1 = {};
        #pragma unroll
        for (int kx = 0; kx < 8; ++kx) {
            acc0 = __builtin_amdgcn_mfma_f32_16x16x32_bf16(xa[kx], wX[kx][0], acc0, 0, 0, 0);
            acc1 = __builtin_amdgcn_mfma_f32_16x16x32_bf16(xa[kx], wX[kx][1], acc1, 0, 0, 0);
        }
        // t=0: h_prev == 0 -> no staging, no h-MFMAs
        if (t > 0) {
            // poll-stage 64B/thread of h_{t-1} from buf[(t-1)%4]:
            // accept when no dword is the sentinel (readiness is in-band)
            {
                const u64* s64 = (const u64*)((const char*)hb +
                                  ((uint)((t + 3) & 3) << 18) + soff);
                u64 hv[8];
                uint dirty = 1u;
                do {
                    if (dirty) {
                        #pragma unroll
                        for (int i = 0; i < 8; ++i)
                            hv[i] = __hip_atomic_load(&s64[i], __ATOMIC_RELAXED,
                                                      __HIP_MEMORY_SCOPE_SYSTEM);
                        dirty = 0u;
                        #pragma unroll
                        for (int i = 0; i < 8; ++i) {
                            if ((uint)(hv[i] & 0xFFFFFFFFull) == SENT32 ||
                                (uint)(hv[i] >> 32) == SENT32)
                                dirty = 1u;
                        }
                    }
                } while (__ballot(dirty != 0u) != 0ull);
                u64* dst64 = (u64*)&hstage[sk8 * 17u + sqt * 4u];
                #pragma unroll
                for (int i = 0; i < 8; ++i) dst64[i] = hv[i];
            }
            __syncthreads();
            // h-path MFMAs from LDS
            #pragma unroll
            for (int it = 0; it < 16; ++it) {
                short8 a = hstage[((uint)it * 4u + quad) * 17u + m];
                acc0 = __builtin_amdgcn_mfma_f32_16x16x32_bf16(a, wH[it][0], acc0, 0, 0, 0);
                acc1 = __builtin_amdgcn_mfma_f32_16x16x32_bf16(a, wH[it][1], acc1, 0, 0, 0);
            }
        }
        // gate tiles -> LDS for cross-wave combine
        #pragma unroll
        for (int r = 0; r < 4; ++r) {
            gtile[(q * 16u + quad * 4u + (uint)r) * 34u + m]        = acc0[r];
            gtile[(q * 16u + quad * 4u + (uint)r) * 34u + 16u + m] = acc1[r];
        }
        __syncthreads();
        // elementwise LSTM epilogue: 2 (b,u) elements per thread
        {
            float ge[4][2];
            #pragma unroll
            for (int g = 0; g < 4; ++g) {
                floatx2 v = *(const floatx2*)&gtile[((uint)g * 16u + eb) * 34u + eu];
                ge[g][0] = v[0]; ge[g][1] = v[1];
            }
            float i0 = fsigmoid(ge[0][0] + vbi0), i1 = fsigmoid(ge[0][1] + vbi1);
            float f0 = fsigmoid(ge[1][0] + vbf0), f1 = fsigmoid(ge[1][1] + vbf1);
            float g0 = ftanh(ge[2][0] + vbg0),    g1 = ftanh(ge[2][1] + vbg1);
            float o0 = fsigmoid(ge[3][0] + vbo0), o1 = fsigmoid(ge[3][1] + vbo1);
            c0 = f0 * c0 + i0 * g0;
            c1 = f1 * c1 + i1 * g1;
            float hv0 = o0 * ftanh(c0);
            float hv1 = o1 * ftanh(c1);
            uint hpack = (uint)f2b(hv0) | ((uint)f2b(hv1) << 16);
            // reset the h_{t-2} slot (will hold h_{t+2}) to sentinel;
            // publish h_t. Order between these two is irrelevant; the
            // end-of-step vmcnt(0) orders both before step t+1's stores.
            uint* hrst = (uint*)((char*)hb + ((uint)((t + 2) & 3) << 18));
            uint* hout = (uint*)((char*)hb + ((uint)(t & 3) << 18));
            __hip_atomic_store(&hrst[hidx], SENT32,
                               __ATOMIC_RELAXED, __HIP_MEMORY_SCOPE_SYSTEM);
            __hip_atomic_store(&hout[hidx], hpack,
                               __ATOMIC_RELAXED, __HIP_MEMORY_SCOPE_SYSTEM);
            if (t == SEQT - 1) {
                floatx2 ov; ov[0] = hv0; ov[1] = hv1;
                *(floatx2*)&out[gb * HID + gu] = ov;
            }
        }
        // commit h_t + sentinel resets before any step-t+1 store can issue
        __asm__ __volatile__("s_waitcnt vmcnt(0)" ::: "memory");
        __syncthreads();
        #pragma unroll
        for (int kx = 0; kx < 8; ++kx) xa[kx] = xn[kx];
    }
}

extern "C" void kernel_launch(void* const* d_in, const int* in_sizes, int n_in,
                              void* d_out, int out_size, void* d_ws, size_t ws_size,
                              hipStream_t stream)
{
    (void)in_sizes; (void)n_in; (void)out_size; (void)ws_size;

    const float* x   = (const float*)d_in[0];
    const float* wui = (const float*)d_in[1];
    const float* whi = (const float*)d_in[2];
    const float* bi  = (const float*)d_in[3];
    const float* wuf = (const float*)d_in[4];
    const float* whf = (const float*)d_in[5];
    const float* bfr = (const float*)d_in[6];
    const float* wug = (const float*)d_in[7];
    const float* whg = (const float*)d_in[8];
    const float* bg  = (const float*)d_in[9];
    const float* wuo = (const float*)d_in[10];
    const float* who = (const float*)d_in[11];
    const float* bo  = (const float*)d_in[12];

    char* ws = (char*)d_ws;
    ushort* hb    = (ushort*)(ws);             // 4 x 256 KB h buffers
    ushort* whp   = (ushort*)(ws + 1048576);   // 2 MB    packed W_h bf16
    ushort* wup   = (ushort*)(ws + 3145728);   // 1 MB    packed W_u bf16
    ushort* xp    = (ushort*)(ws + 4194304);   // 64 MB   x bf16

    // Sentinel-fill h buffers 0 and 1 (polled at steps 1,2). Buffers 2,3
    // are reset in-kernel at steps 0,1 before they are ever polled.
    hipMemsetAsync(hb, 0x7F, 524288, stream);
    pack_x<<<32768, 256, 0, stream>>>((const float4v*)x, xp);
    pack_weights<<<6144, 256, 0, stream>>>(whi, whf, whg, who,
                                           wui, wuf, wug, wuo, whp, wup);

    lstm_persist<<<256, 256, 0, stream>>>(
        (const short8*)xp, (const short8*)whp, (const short8*)wup,
        bi, bfr, bg, bo, hb, (float*)d_out);
}